// Round 3
// baseline (451.310 us; speedup 1.0000x reference)
//
#include <hip/hip_runtime.h>

#define HS 4096  // HIDDEN_SIZE == INPUT_SIZE == 4096

// One wave (64 lanes) per output row: computes all 8 dot products (4 gates x
// {W@x, W@h}) of length 4096 in fp32, wave-reduces, lane 0 applies gating and
// writes fp32 outputs. Block = 256 threads = 4 waves = 4 rows; grid = 1024.
__global__ __launch_bounds__(256) void lstm_step(
    const float* __restrict__ x,
    const float* __restrict__ hprev,
    const float* __restrict__ cprev,
    const float* __restrict__ Wii, const float* __restrict__ Wif,
    const float* __restrict__ Wig, const float* __restrict__ Wio,
    const float* __restrict__ Whi, const float* __restrict__ Whf,
    const float* __restrict__ Whg, const float* __restrict__ Who,
    const float* __restrict__ bii, const float* __restrict__ bif_,
    const float* __restrict__ big_, const float* __restrict__ bio,
    const float* __restrict__ bhi, const float* __restrict__ bhf,
    const float* __restrict__ bhg, const float* __restrict__ bho,
    float* __restrict__ out, int mode)
{
  __shared__ float4 sx[HS / 4];  // x: 1024 float4 = 16 KB
  __shared__ float4 sh[HS / 4];  // h_prev: 16 KB
  const int tid = threadIdx.x;
  const float4* gx = (const float4*)x;
  const float4* gh = (const float4*)hprev;
#pragma unroll
  for (int c = 0; c < 4; ++c) {
    sx[tid + 256 * c] = gx[tid + 256 * c];
    sh[tid + 256 * c] = gh[tid + 256 * c];
  }
  __syncthreads();

  const int wave = tid >> 6;
  const int lane = tid & 63;
  const int row = (blockIdx.x << 2) + wave;

  const float* Wx[4] = {Wii, Wif, Wig, Wio};
  const float* Wh[4] = {Whi, Whf, Whg, Who};
  float acc[4];
#pragma unroll
  for (int g = 0; g < 4; ++g) {
    float a = 0.f;
    const float4* wr = (const float4*)(Wx[g]) + (size_t)row * (HS / 4);
    const float4* hr = (const float4*)(Wh[g]) + (size_t)row * (HS / 4);
#pragma unroll
    for (int j = 0; j < 16; ++j) {
      const float4 w = wr[(j << 6) + lane];
      const float4 v = sx[(j << 6) + lane];
      a = fmaf(w.x, v.x, a);
      a = fmaf(w.y, v.y, a);
      a = fmaf(w.z, v.z, a);
      a = fmaf(w.w, v.w, a);
    }
#pragma unroll
    for (int j = 0; j < 16; ++j) {
      const float4 w = hr[(j << 6) + lane];
      const float4 v = sh[(j << 6) + lane];
      a = fmaf(w.x, v.x, a);
      a = fmaf(w.y, v.y, a);
      a = fmaf(w.z, v.z, a);
      a = fmaf(w.w, v.w, a);
    }
    acc[g] = a;
  }

  // butterfly wave reduction across 64 lanes
#pragma unroll
  for (int g = 0; g < 4; ++g) {
#pragma unroll
    for (int off = 32; off > 0; off >>= 1)
      acc[g] += __shfl_xor(acc[g], off, 64);
  }

  if (lane == 0) {
    const float zi = acc[0] + bii[row] + bhi[row];
    const float zf = acc[1] + bif_[row] + bhf[row];
    const float zg = acc[2] + big_[row] + bhg[row];
    const float zo = acc[3] + bio[row] + bho[row];
    const float it = 1.f / (1.f + __expf(-zi));
    const float ft = 1.f / (1.f + __expf(-zf));
    const float gt = tanhf(zg);
    const float ot = 1.f / (1.f + __expf(-zo));
    const float ct = ft * cprev[row] + it * gt;
    const float ht = ot * tanhf(ct);
    // reference returns (h_t, (h_t, c_t)) -> flat [h_t, h_t, c_t]
    out[row] = ht;
    if (mode >= 3) {
      out[HS + row] = ht;
      out[2 * HS + row] = ct;
    } else if (mode == 2) {
      out[HS + row] = ct;
    }
  }
}

extern "C" void kernel_launch(void* const* d_in, const int* in_sizes, int n_in,
                              void* d_out, int out_size, void* d_ws, size_t ws_size,
                              hipStream_t stream) {
  const float* p[19];
  for (int i = 0; i < 19; ++i) p[i] = (const float*)d_in[i];
  const int mode = out_size / HS;  // 3 expected: [h_t, h_t, c_t]
  lstm_step<<<HS / 4, 256, 0, stream>>>(
      p[0], p[1], p[2],
      p[3], p[4], p[5], p[6],
      p[7], p[8], p[9], p[10],
      p[11], p[12], p[13], p[14],
      p[15], p[16], p[17], p[18],
      (float*)d_out, mode);
}